// Round 2
// baseline (288.109 us; speedup 1.0000x reference)
//
#include <hip/hip_runtime.h>

// Non-local attention: X [8, 64, 64, 64] fp32.
// Per batch b: Q=K=V = X_b^T  [S=4096, D=64];  out = softmax(Q K^T) V, stored [b][c][s].
//
// R2 structure:
//   prepass: X fp32 [c][m] -> ws: Xbf bf16 [c][m] (4MB) + XbfT bf16 [m][c] (4MB)
//   main:    flash attention, 4 independent waves/block (16 Q-rows each),
//            ALL MFMA fragments loaded directly from global (coalesced 16B),
//            no barriers in the K-loop, K-frags register-double-buffered.

#define SEQ 4096
#define DIM 64
#define LDB 72   // bf16 LDS row stride for sP / prepass transpose (144B, 16B-aligned)
#define LDO 68   // fp32 LDS row stride for epilogue transpose

typedef __attribute__((ext_vector_type(8))) short  short8;  // 8 bf16 = 4 VGPRs
typedef __attribute__((ext_vector_type(4))) float  f32x4;

__device__ __forceinline__ unsigned short f2bf(float f) {
    union { float f; unsigned int u; } x; x.f = f;
    unsigned int u = x.u + 0x7FFFu + ((x.u >> 16) & 1u);   // RNE
    return (unsigned short)(u >> 16);
}

// ---------------- prepass: bf16 cast + transpose (once per call, ~5us) ----------------
__global__ __launch_bounds__(256) void prepass_kernel(const float* __restrict__ X,
                                                      unsigned short* __restrict__ Xbf,
                                                      unsigned short* __restrict__ XbfT) {
    __shared__ __align__(16) unsigned short sT[64 * LDB];
    const int b = blockIdx.y, m0 = blockIdx.x * 64;
    const float* Xb = X + (size_t)b * DIM * SEQ;
    unsigned short* Bb = Xbf  + (size_t)b * DIM * SEQ;
    unsigned short* Tb = XbfT + (size_t)b * SEQ * DIM;
    const int tid = threadIdx.x;
    const int mgrp = tid & 15, c0 = tid >> 4;
    #pragma unroll
    for (int cc = 0; cc < 4; ++cc) {
        const int c = c0 + 16 * cc;
        const f32x4 v = *(const f32x4*)(Xb + (size_t)c * SEQ + m0 + 4 * mgrp);
        const ushort4 h = make_ushort4(f2bf(v.x), f2bf(v.y), f2bf(v.z), f2bf(v.w));
        *(ushort4*)(Bb + (size_t)c * SEQ + m0 + 4 * mgrp) = h;
        sT[(4 * mgrp + 0) * LDB + c] = h.x;    // conflicted, but once per 64 elems, not per-iter
        sT[(4 * mgrp + 1) * LDB + c] = h.y;
        sT[(4 * mgrp + 2) * LDB + c] = h.z;
        sT[(4 * mgrp + 3) * LDB + c] = h.w;
    }
    __syncthreads();
    const int m = tid >> 2, cg = tid & 3;
    const short8 a0 = *(const short8*)(sT + m * LDB + cg * 8);
    const short8 a1 = *(const short8*)(sT + m * LDB + 32 + cg * 8);
    *(short8*)(Tb + (size_t)(m0 + m) * DIM + cg * 8)      = a0;
    *(short8*)(Tb + (size_t)(m0 + m) * DIM + 32 + cg * 8) = a1;
}

// ---------------- main attention kernel (barrier-free K-loop) ----------------
__device__ __forceinline__ void load_k(const unsigned short* __restrict__ Tb, int kt,
                                       int l15, int quad, short8 kf[2][4]) {
    const unsigned short* kp = Tb + (size_t)(kt * 64 + l15) * DIM + quad * 8;
    #pragma unroll
    for (int mt = 0; mt < 4; ++mt) {
        kf[0][mt] = *(const short8*)(kp + mt * 16 * DIM);
        kf[1][mt] = *(const short8*)(kp + mt * 16 * DIM + 32);
    }
}

__global__ __launch_bounds__(256, 2) void attn_main(const unsigned short* __restrict__ Xbf,
                                                    const unsigned short* __restrict__ XbfT,
                                                    float* __restrict__ Out) {
    __shared__ __align__(16) unsigned short sP[64 * LDB];   // per-wave 16-row strips
    __shared__ __align__(16) float          sO[64 * LDO];

    const int tid  = threadIdx.x;
    const int lane = tid & 63;
    const int w    = tid >> 6;
    const int l15  = lane & 15;
    const int quad = lane >> 4;

    const int b  = blockIdx.y;
    const int s0 = blockIdx.x * 64;
    const unsigned short* Bb = Xbf  + (size_t)b * DIM * SEQ;
    const unsigned short* Tb = XbfT + (size_t)b * SEQ * DIM;

    // Q A-frags straight from transposed global (row = this lane's Q row)
    const unsigned short* qp = Tb + (size_t)(s0 + 16 * w + l15) * DIM + quad * 8;
    const short8 qf0 = *(const short8*)(qp);
    const short8 qf1 = *(const short8*)(qp + 32);

    f32x4 acc_o[4];
    #pragma unroll
    for (int ct = 0; ct < 4; ++ct) acc_o[ct] = (f32x4){0.f, 0.f, 0.f, 0.f};
    float m_i[4] = {-1e30f, -1e30f, -1e30f, -1e30f};
    float l_i[4] = {0.f, 0.f, 0.f, 0.f};

    unsigned short* sPw = sP + 16 * w * LDB;   // this wave's private strip

    auto compute = [&](int kt, short8 kf[2][4]) {
        // V B-frags: issued now, consumed after softmax (~400cyc of slack)
        const unsigned short* vp = Bb + (size_t)l15 * SEQ + kt * 64 + quad * 8;
        short8 vf[2][4];
        #pragma unroll
        for (int ct = 0; ct < 4; ++ct) {
            vf[0][ct] = *(const short8*)(vp + (size_t)ct * 16 * SEQ);
            vf[1][ct] = *(const short8*)(vp + (size_t)ct * 16 * SEQ + 32);
        }

        // S = Q K^T  (16 rows x 64 cols per wave)
        f32x4 acc_s[4];
        #pragma unroll
        for (int mt = 0; mt < 4; ++mt) {
            f32x4 a = (f32x4){0.f, 0.f, 0.f, 0.f};
            a = __builtin_amdgcn_mfma_f32_16x16x32_bf16(qf0, kf[0][mt], a, 0, 0, 0);
            a = __builtin_amdgcn_mfma_f32_16x16x32_bf16(qf1, kf[1][mt], a, 0, 0, 0);
            acc_s[mt] = a;
        }

        // online softmax across the 64 columns
        float alpha[4];
        #pragma unroll
        for (int r = 0; r < 4; ++r) {
            float mx = fmaxf(fmaxf(acc_s[0][r], acc_s[1][r]), fmaxf(acc_s[2][r], acc_s[3][r]));
            mx = fmaxf(mx, __shfl_xor(mx, 1));
            mx = fmaxf(mx, __shfl_xor(mx, 2));
            mx = fmaxf(mx, __shfl_xor(mx, 4));
            mx = fmaxf(mx, __shfl_xor(mx, 8));
            const float mnew = fmaxf(m_i[r], mx);
            alpha[r] = __expf(m_i[r] - mnew);
            m_i[r] = mnew;
        }
        float rowsum[4] = {0.f, 0.f, 0.f, 0.f};
        unsigned short pb[4][4];
        #pragma unroll
        for (int mt = 0; mt < 4; ++mt)
            #pragma unroll
            for (int r = 0; r < 4; ++r) {
                const float p = __expf(acc_s[mt][r] - m_i[r]);
                rowsum[r] += p;
                pb[mt][r] = f2bf(p);
            }
        #pragma unroll
        for (int r = 0; r < 4; ++r) {
            float s = rowsum[r];
            s += __shfl_xor(s, 1);
            s += __shfl_xor(s, 2);
            s += __shfl_xor(s, 4);
            s += __shfl_xor(s, 8);
            l_i[r] = alpha[r] * l_i[r] + s;
        }
        #pragma unroll
        for (int ct = 0; ct < 4; ++ct)
            #pragma unroll
            for (int r = 0; r < 4; ++r)
                acc_o[ct][r] *= alpha[r];

        // P: C-layout -> wave-private LDS strip -> A-layout frags (no barrier: same wave)
        #pragma unroll
        for (int mt = 0; mt < 4; ++mt)
            #pragma unroll
            for (int r = 0; r < 4; ++r)
                sPw[(quad * 4 + r) * LDB + l15 + 16 * mt] = pb[mt][r];
        const short8 pf0 = *(const short8*)(sPw + l15 * LDB + quad * 8);
        const short8 pf1 = *(const short8*)(sPw + l15 * LDB + 32 + quad * 8);
        #pragma unroll
        for (int ct = 0; ct < 4; ++ct) {
            acc_o[ct] = __builtin_amdgcn_mfma_f32_16x16x32_bf16(pf0, vf[0][ct], acc_o[ct], 0, 0, 0);
            acc_o[ct] = __builtin_amdgcn_mfma_f32_16x16x32_bf16(pf1, vf[1][ct], acc_o[ct], 0, 0, 0);
        }
    };

    // K-frag register double-buffer: loads for kt+1 in flight during compute(kt)
    short8 kA[2][4], kB[2][4];
    load_k(Tb, 0, l15, quad, kA);
    for (int kt = 0; kt < SEQ / 64; kt += 2) {
        load_k(Tb, kt + 1, l15, quad, kB);
        compute(kt, kA);
        if (kt + 2 < SEQ / 64) load_k(Tb, kt + 2, l15, quad, kA);
        compute(kt + 1, kB);
    }

    // epilogue: O/l, transpose via LDS for coalesced [c][s] stores
    float inv[4];
    #pragma unroll
    for (int r = 0; r < 4; ++r) inv[r] = 1.f / l_i[r];
    #pragma unroll
    for (int ct = 0; ct < 4; ++ct) {
        const int c = 16 * ct + l15;
        #pragma unroll
        for (int r = 0; r < 4; ++r)
            sO[c * LDO + 16 * w + quad * 4 + r] = acc_o[ct][r] * inv[r];
    }
    __syncthreads();
    const int mgrp = tid & 15, c0 = tid >> 4;
    #pragma unroll
    for (int cc = 0; cc < 4; ++cc) {
        const int c = c0 + 16 * cc;
        const f32x4 v = *(const f32x4*)(sO + c * LDO + 4 * mgrp);
        *(f32x4*)(Out + (size_t)b * DIM * SEQ + (size_t)c * SEQ + s0 + 4 * mgrp) = v;
    }
}

// ---------------- fallback (proven R1 kernel) if ws is too small ----------------
__global__ __launch_bounds__(256, 2) void attn_fallback(const float* __restrict__ X,
                                                        float* __restrict__ Out) {
    __shared__ __align__(16) unsigned char smem[27648];
    unsigned short* sK = (unsigned short*)smem;
    unsigned short* sV = (unsigned short*)(smem + 9216);
    unsigned short* sP = (unsigned short*)(smem + 18432);
    float*          sO = (float*)smem;

    const int tid  = threadIdx.x;
    const int lane = tid & 63;
    const int w    = tid >> 6;
    const int l15  = lane & 15;
    const int quad = lane >> 4;
    const int b  = blockIdx.y;
    const int s0 = blockIdx.x * 64;
    const float* Xb = X + (size_t)b * DIM * SEQ;
    const int mgrp = tid & 15;
    const int c0   = tid >> 4;

    for (int cc = 0; cc < 4; ++cc) {
        int c = c0 + 16 * cc;
        const f32x4 v = *(const f32x4*)(Xb + (size_t)c * SEQ + s0 + 4 * mgrp);
        sK[(4 * mgrp + 0) * LDB + c] = f2bf(v.x);
        sK[(4 * mgrp + 1) * LDB + c] = f2bf(v.y);
        sK[(4 * mgrp + 2) * LDB + c] = f2bf(v.z);
        sK[(4 * mgrp + 3) * LDB + c] = f2bf(v.w);
    }
    __syncthreads();
    short8 qf0, qf1;
    {
        const int row = 16 * w + l15;
        qf0 = *(const short8*)(sK + row * LDB + quad * 8);
        qf1 = *(const short8*)(sK + row * LDB + 32 + quad * 8);
    }
    __syncthreads();

    f32x4 acc_o[4];
    for (int ct = 0; ct < 4; ++ct) acc_o[ct] = (f32x4){0.f, 0.f, 0.f, 0.f};
    float m_i[4] = {-1e30f, -1e30f, -1e30f, -1e30f};
    float l_i[4] = {0.f, 0.f, 0.f, 0.f};

    for (int kt = 0; kt < SEQ / 64; ++kt) {
        const int m0 = kt * 64;
        for (int cc = 0; cc < 4; ++cc) {
            int c = c0 + 16 * cc;
            const f32x4 v = *(const f32x4*)(Xb + (size_t)c * SEQ + m0 + 4 * mgrp);
            unsigned short h0 = f2bf(v.x), h1 = f2bf(v.y), h2 = f2bf(v.z), h3 = f2bf(v.w);
            *(ushort4*)(sV + c * LDB + 4 * mgrp) = make_ushort4(h0, h1, h2, h3);
            sK[(4 * mgrp + 0) * LDB + c] = h0;
            sK[(4 * mgrp + 1) * LDB + c] = h1;
            sK[(4 * mgrp + 2) * LDB + c] = h2;
            sK[(4 * mgrp + 3) * LDB + c] = h3;
        }
        __syncthreads();

        short8 vf[2][4];
        for (int ks = 0; ks < 2; ++ks)
            for (int ct = 0; ct < 4; ++ct)
                vf[ks][ct] = *(const short8*)(sV + (16 * ct + l15) * LDB + ks * 32 + quad * 8);

        f32x4 acc_s[4];
        for (int mt = 0; mt < 4; ++mt) {
            const int row = 16 * mt + l15;
            const short8 kf0 = *(const short8*)(sK + row * LDB + quad * 8);
            const short8 kf1 = *(const short8*)(sK + row * LDB + 32 + quad * 8);
            f32x4 a = (f32x4){0.f, 0.f, 0.f, 0.f};
            a = __builtin_amdgcn_mfma_f32_16x16x32_bf16(qf0, kf0, a, 0, 0, 0);
            a = __builtin_amdgcn_mfma_f32_16x16x32_bf16(qf1, kf1, a, 0, 0, 0);
            acc_s[mt] = a;
        }

        float alpha[4];
        for (int r = 0; r < 4; ++r) {
            float mx = fmaxf(fmaxf(acc_s[0][r], acc_s[1][r]), fmaxf(acc_s[2][r], acc_s[3][r]));
            mx = fmaxf(mx, __shfl_xor(mx, 1));
            mx = fmaxf(mx, __shfl_xor(mx, 2));
            mx = fmaxf(mx, __shfl_xor(mx, 4));
            mx = fmaxf(mx, __shfl_xor(mx, 8));
            const float mnew = fmaxf(m_i[r], mx);
            alpha[r] = __expf(m_i[r] - mnew);
            m_i[r] = mnew;
        }
        float rowsum[4] = {0.f, 0.f, 0.f, 0.f};
        unsigned short pb[4][4];
        for (int mt = 0; mt < 4; ++mt)
            for (int r = 0; r < 4; ++r) {
                const float p = __expf(acc_s[mt][r] - m_i[r]);
                rowsum[r] += p;
                pb[mt][r] = f2bf(p);
            }
        for (int r = 0; r < 4; ++r) {
            float s = rowsum[r];
            s += __shfl_xor(s, 1);
            s += __shfl_xor(s, 2);
            s += __shfl_xor(s, 4);
            s += __shfl_xor(s, 8);
            l_i[r] = alpha[r] * l_i[r] + s;
        }
        for (int ct = 0; ct < 4; ++ct)
            for (int r = 0; r < 4; ++r)
                acc_o[ct][r] *= alpha[r];

        for (int mt = 0; mt < 4; ++mt)
            for (int r = 0; r < 4; ++r)
                sP[(16 * w + quad * 4 + r) * LDB + l15 + 16 * mt] = pb[mt][r];
        __syncthreads();

        const short8 pf0 = *(const short8*)(sP + (16 * w + l15) * LDB + quad * 8);
        const short8 pf1 = *(const short8*)(sP + (16 * w + l15) * LDB + 32 + quad * 8);
        for (int ct = 0; ct < 4; ++ct) {
            acc_o[ct] = __builtin_amdgcn_mfma_f32_16x16x32_bf16(pf0, vf[0][ct], acc_o[ct], 0, 0, 0);
            acc_o[ct] = __builtin_amdgcn_mfma_f32_16x16x32_bf16(pf1, vf[1][ct], acc_o[ct], 0, 0, 0);
        }
    }

    float inv[4];
    for (int r = 0; r < 4; ++r) inv[r] = 1.f / l_i[r];
    for (int ct = 0; ct < 4; ++ct) {
        const int c = 16 * ct + l15;
        for (int r = 0; r < 4; ++r)
            sO[c * LDO + 16 * w + quad * 4 + r] = acc_o[ct][r] * inv[r];
    }
    __syncthreads();
    for (int cc = 0; cc < 4; ++cc) {
        const int c = c0 + 16 * cc;
        const f32x4 v = *(const f32x4*)(sO + c * LDO + 4 * mgrp);
        *(f32x4*)(Out + (size_t)b * DIM * SEQ + (size_t)c * SEQ + s0 + 4 * mgrp) = v;
    }
}

extern "C" void kernel_launch(void* const* d_in, const int* in_sizes, int n_in,
                              void* d_out, int out_size, void* d_ws, size_t ws_size,
                              hipStream_t stream) {
    const float* X = (const float*)d_in[0];
    float* Out = (float*)d_out;
    const size_t need = (size_t)8 * SEQ * DIM * 2 * 2;   // Xbf + XbfT, bf16
    if (ws_size >= need) {
        unsigned short* Xbf  = (unsigned short*)d_ws;
        unsigned short* XbfT = Xbf + (size_t)8 * SEQ * DIM;
        dim3 grid(64, 8);
        prepass_kernel<<<grid, 256, 0, stream>>>(X, Xbf, XbfT);
        attn_main<<<grid, 256, 0, stream>>>(Xbf, XbfT, Out);
    } else {
        dim3 grid(SEQ / 64, 8);
        attn_fallback<<<grid, 256, 0, stream>>>(X, Out);
    }
}

// Round 3
// 124.681 us; speedup vs baseline: 2.3108x; 2.3108x over previous
//
#include <hip/hip_runtime.h>

// Non-local attention: X [8, 64, 64, 64] fp32.
// Per batch b: Q=K=V = X_b^T  [S=4096, D=64];  out = softmax(Q K^T) V, stored [b][c][s].
//
// R3: prepass (bf16 cast both layouts + row norms + batch max-norm) then
// flash attention with:
//   - fixed softmax max m_n = ||x_n|| * maxnorm_b  (Cauchy-Schwarz; no online max)
//   - S^T = K.Q^T orientation (lane's scores share one column n -> scalar m_n/lane)
//   - K/V tiles double-buffered in LDS via async global_load_lds (width 16),
//     XOR-chunk swizzle for conflict-free ds_read_b128 fragment reads
//   - P -> LDS via 4x ds_write_b64 (v_perm pack), read back as A-frags

#define SEQ 4096
#define DIM 64
#define LDB 72   // fallback kernel LDS stride
#define LDP 72   // sP row stride (elements); 144B rows -> 2-way bank aliasing (free)
#define LDO 68   // fp32 LDS row stride for epilogue transpose

typedef __attribute__((ext_vector_type(8))) short  short8;  // 8 bf16 = 4 VGPRs
typedef __attribute__((ext_vector_type(4))) float  f32x4;

__device__ __forceinline__ unsigned short f2bf(float f) {
    union { float f; unsigned int u; } x; x.f = f;
    unsigned int u = x.u + 0x7FFFu + ((x.u >> 16) & 1u);   // RNE
    return (unsigned short)(u >> 16);
}
__device__ __forceinline__ float bf2f(unsigned short h) {
    union { unsigned int u; float f; } x; x.u = ((unsigned int)h) << 16; return x.f;
}

// ---------------- prepass: bf16 cast (both layouts) + row norms + batch max ----------------
__global__ __launch_bounds__(256) void prepass2(const float* __restrict__ X,
                                                unsigned short* __restrict__ Xbf,
                                                unsigned short* __restrict__ XbfT,
                                                float* __restrict__ Norms,
                                                float* __restrict__ MaxNorm) {
    __shared__ float sN[16 * 65];
    const int b = blockIdx.y, m0 = blockIdx.x * 64;
    const float* Xb = X + (size_t)b * DIM * SEQ;
    unsigned short* Bb = Xbf  + (size_t)b * DIM * SEQ;
    unsigned short* Tb = XbfT + (size_t)b * SEQ * DIM;
    const int t = threadIdx.x, mw = t & 15, cg = t >> 4;   // 4 m x 4 c micro-tile per thread

    unsigned short hb[4][4];   // [cr][mr]
    #pragma unroll
    for (int cr = 0; cr < 4; ++cr) {
        const int c = cg * 4 + cr;
        const f32x4 v = *(const f32x4*)(Xb + (size_t)c * SEQ + m0 + mw * 4);
        hb[cr][0] = f2bf(v.x); hb[cr][1] = f2bf(v.y); hb[cr][2] = f2bf(v.z); hb[cr][3] = f2bf(v.w);
        *(ushort4*)(Bb + (size_t)c * SEQ + m0 + mw * 4) =
            make_ushort4(hb[cr][0], hb[cr][1], hb[cr][2], hb[cr][3]);
    }
    #pragma unroll
    for (int mr = 0; mr < 4; ++mr) {
        float nrm = 0.f;
        #pragma unroll
        for (int cr = 0; cr < 4; ++cr) { const float fv = bf2f(hb[cr][mr]); nrm += fv * fv; }
        *(ushort4*)(Tb + (size_t)(m0 + mw * 4 + mr) * DIM + cg * 4) =
            make_ushort4(hb[0][mr], hb[1][mr], hb[2][mr], hb[3][mr]);
        sN[cg * 65 + mw * 4 + mr] = nrm;   // norms from bf16 values -> exact C-S bound later
    }
    __syncthreads();
    if (t < 64) {                      // wave 0
        float s = 0.f;
        #pragma unroll
        for (int i = 0; i < 16; ++i) s += sN[i * 65 + t];
        const float nm = sqrtf(s);
        Norms[(size_t)b * SEQ + m0 + t] = nm;
        float mx = nm;
        #pragma unroll
        for (int d = 1; d < 64; d <<= 1) mx = fmaxf(mx, __shfl_xor(mx, d));
        if (t == 0) atomicMax((unsigned int*)(MaxNorm + b), __float_as_uint(mx));
    }
}

// ---------------- main attention kernel ----------------
__global__ __launch_bounds__(256, 2) void attn_main(const unsigned short* __restrict__ Xbf,
                                                    const unsigned short* __restrict__ XbfT,
                                                    const float* __restrict__ Norms,
                                                    const float* __restrict__ MaxNorm,
                                                    float* __restrict__ Out) {
    // smem: sK 2x8KB dbuf | sV 2x8KB dbuf | sP 4 wave strips; sO (fp32 17408B) overlays sK/sV
    __shared__ __align__(16) unsigned char smem[16384 + 16384 + 4 * 16 * LDP * 2];
    unsigned short* sK = (unsigned short*)smem;
    unsigned short* sV = (unsigned short*)(smem + 16384);
    unsigned short* sP = (unsigned short*)(smem + 32768);
    float*          sO = (float*)smem;

    const int tid  = threadIdx.x;
    const int lane = tid & 63;
    const int w    = tid >> 6;
    const int l15  = lane & 15;
    const int quad = lane >> 4;

    const int b  = blockIdx.y;
    const int s0 = blockIdx.x * 64;
    const unsigned short* Bb = Xbf  + (size_t)b * DIM * SEQ;
    const unsigned short* Tb = XbfT + (size_t)b * SEQ * DIM;

    // Q fragments (B-operand for S^T = K.Q^T): this wave's 16 Q rows
    const unsigned short* qp = Tb + (size_t)(s0 + 16 * w + l15) * DIM + quad * 8;
    const short8 qf0 = *(const short8*)(qp);
    const short8 qf1 = *(const short8*)(qp + 32);

    // fixed softmax bound for this lane's column n = l15  (C-S: s <= ||x_n||*maxnorm)
    const float mrow = Norms[(size_t)b * SEQ + s0 + 16 * w + l15] * MaxNorm[b];

    f32x4 acc_o[4];
    #pragma unroll
    for (int ct = 0; ct < 4; ++ct) acc_o[ct] = (f32x4){0.f, 0.f, 0.f, 0.f};
    float lpart = 0.f;
    unsigned short* sPw = sP + w * 16 * LDP;

    // async stage: lane chunk l -> tile (row=(2w+j)*8 + (l>>3), cg'=l&7), global cg = cg'^row&7
    const int rl = lane >> 3, cgp = lane & 7;
    const int cgs = cgp ^ rl;
    auto stage = [&](int kt, int half) {
        unsigned short* sKb = sK + half * 4096;
        unsigned short* sVb = sV + half * 4096;
        #pragma unroll
        for (int j = 0; j < 2; ++j) {
            const int row = (2 * w + j) * 8 + rl;
            const unsigned short* gK = Tb + ((size_t)(kt * 64 + row) << 6) + (cgs << 3);
            const unsigned short* gV = Bb + (((size_t)row) << 12) + (kt << 6) + (cgs << 3);
            __builtin_amdgcn_global_load_lds(
                (const __attribute__((address_space(1))) unsigned int*)gK,
                (__attribute__((address_space(3))) unsigned int*)(sKb + ((2 * w + j) << 9)),
                16, 0, 0);
            __builtin_amdgcn_global_load_lds(
                (const __attribute__((address_space(1))) unsigned int*)gV,
                (__attribute__((address_space(3))) unsigned int*)(sVb + ((2 * w + j) << 9)),
                16, 0, 0);
        }
    };

    const int rsw = l15 & 7;
    auto compute = [&](int half) {
        const unsigned short* sKc = sK + half * 4096;
        const unsigned short* sVc = sV + half * 4096;
        short8 kf[2][4], vf[2][4];
        #pragma unroll
        for (int t4 = 0; t4 < 4; ++t4) {
            const int rowoff = (16 * t4 + l15) << 6;
            #pragma unroll
            for (int ks = 0; ks < 2; ++ks) {
                const int cgr = (((quad + 4 * ks) ^ rsw) << 3);
                kf[ks][t4] = *(const short8*)(sKc + rowoff + cgr);
                vf[ks][t4] = *(const short8*)(sVc + rowoff + cgr);
            }
        }
        // S^T tiles: D[m_local][n=l15]; lane holds m = 16*mt + 4*quad + r
        #pragma unroll
        for (int mt = 0; mt < 4; ++mt) {
            f32x4 a = (f32x4){0.f, 0.f, 0.f, 0.f};
            a = __builtin_amdgcn_mfma_f32_16x16x32_bf16(kf[0][mt], qf0, a, 0, 0, 0);
            a = __builtin_amdgcn_mfma_f32_16x16x32_bf16(kf[1][mt], qf1, a, 0, 0, 0);
            const float p0 = __expf(a[0] - mrow);
            const float p1 = __expf(a[1] - mrow);
            const float p2 = __expf(a[2] - mrow);
            const float p3 = __expf(a[3] - mrow);
            lpart += (p0 + p1) + (p2 + p3);
            const unsigned u0 = __float_as_uint(p0) + 0x8000u;
            const unsigned u1 = __float_as_uint(p1) + 0x8000u;
            const unsigned u2 = __float_as_uint(p2) + 0x8000u;
            const unsigned u3 = __float_as_uint(p3) + 0x8000u;
            const unsigned lo = __builtin_amdgcn_perm(u1, u0, 0x07060302u);  // bf(p1)<<16|bf(p0)
            const unsigned hi = __builtin_amdgcn_perm(u3, u2, 0x07060302u);
            *(uint2*)(sPw + l15 * LDP + 16 * mt + quad * 4) = make_uint2(lo, hi);
        }
        // P A-frags (wave-private strip; compiler orders lgkmcnt)
        const short8 pf0 = *(const short8*)(sPw + l15 * LDP + quad * 8);
        const short8 pf1 = *(const short8*)(sPw + l15 * LDP + 32 + quad * 8);
        #pragma unroll
        for (int ct = 0; ct < 4; ++ct) {
            acc_o[ct] = __builtin_amdgcn_mfma_f32_16x16x32_bf16(pf0, vf[0][ct], acc_o[ct], 0, 0, 0);
            acc_o[ct] = __builtin_amdgcn_mfma_f32_16x16x32_bf16(pf1, vf[1][ct], acc_o[ct], 0, 0, 0);
        }
    };

    stage(0, 0);
    __syncthreads();
    for (int kt = 0; kt < 64; kt += 2) {
        stage(kt + 1, 1);          // async into other half while computing this one
        compute(0);
        __syncthreads();
        if (kt + 2 < 64) stage(kt + 2, 0);
        compute(1);
        __syncthreads();
    }

    // row sums: reduce lane partials across quads (all lanes end with lsum(n=l15))
    lpart += __shfl_xor(lpart, 16);
    lpart += __shfl_xor(lpart, 32);
    float inv[4];
    #pragma unroll
    for (int r = 0; r < 4; ++r) inv[r] = 1.f / __shfl(lpart, 4 * quad + r);

    #pragma unroll
    for (int ct = 0; ct < 4; ++ct) {
        const int c = 16 * ct + l15;
        #pragma unroll
        for (int r = 0; r < 4; ++r)
            sO[c * LDO + 16 * w + quad * 4 + r] = acc_o[ct][r] * inv[r];
    }
    __syncthreads();
    const int mgrp = tid & 15, c0 = tid >> 4;
    #pragma unroll
    for (int cc = 0; cc < 4; ++cc) {
        const int c = c0 + 16 * cc;
        const f32x4 v = *(const f32x4*)(sO + c * LDO + 4 * mgrp);
        *(f32x4*)(Out + (size_t)b * DIM * SEQ + (size_t)c * SEQ + s0 + 4 * mgrp) = v;
    }
}

// ---------------- fallback (proven R1 kernel) if ws is too small ----------------
__global__ __launch_bounds__(256, 2) void attn_fallback(const float* __restrict__ X,
                                                        float* __restrict__ Out) {
    __shared__ __align__(16) unsigned char smem[27648];
    unsigned short* sK = (unsigned short*)smem;
    unsigned short* sV = (unsigned short*)(smem + 9216);
    unsigned short* sP = (unsigned short*)(smem + 18432);
    float*          sO = (float*)smem;

    const int tid  = threadIdx.x;
    const int lane = tid & 63;
    const int w    = tid >> 6;
    const int l15  = lane & 15;
    const int quad = lane >> 4;
    const int b  = blockIdx.y;
    const int s0 = blockIdx.x * 64;
    const float* Xb = X + (size_t)b * DIM * SEQ;
    const int mgrp = tid & 15;
    const int c0   = tid >> 4;

    for (int cc = 0; cc < 4; ++cc) {
        int c = c0 + 16 * cc;
        const f32x4 v = *(const f32x4*)(Xb + (size_t)c * SEQ + s0 + 4 * mgrp);
        sK[(4 * mgrp + 0) * LDB + c] = f2bf(v.x);
        sK[(4 * mgrp + 1) * LDB + c] = f2bf(v.y);
        sK[(4 * mgrp + 2) * LDB + c] = f2bf(v.z);
        sK[(4 * mgrp + 3) * LDB + c] = f2bf(v.w);
    }
    __syncthreads();
    short8 qf0, qf1;
    {
        const int row = 16 * w + l15;
        qf0 = *(const short8*)(sK + row * LDB + quad * 8);
        qf1 = *(const short8*)(sK + row * LDB + 32 + quad * 8);
    }
    __syncthreads();

    f32x4 acc_o[4];
    for (int ct = 0; ct < 4; ++ct) acc_o[ct] = (f32x4){0.f, 0.f, 0.f, 0.f};
    float m_i[4] = {-1e30f, -1e30f, -1e30f, -1e30f};
    float l_i[4] = {0.f, 0.f, 0.f, 0.f};

    for (int kt = 0; kt < SEQ / 64; ++kt) {
        const int m0 = kt * 64;
        for (int cc = 0; cc < 4; ++cc) {
            int c = c0 + 16 * cc;
            const f32x4 v = *(const f32x4*)(Xb + (size_t)c * SEQ + m0 + 4 * mgrp);
            unsigned short h0 = f2bf(v.x), h1 = f2bf(v.y), h2 = f2bf(v.z), h3 = f2bf(v.w);
            *(ushort4*)(sV + c * LDB + 4 * mgrp) = make_ushort4(h0, h1, h2, h3);
            sK[(4 * mgrp + 0) * LDB + c] = h0;
            sK[(4 * mgrp + 1) * LDB + c] = h1;
            sK[(4 * mgrp + 2) * LDB + c] = h2;
            sK[(4 * mgrp + 3) * LDB + c] = h3;
        }
        __syncthreads();

        short8 vf[2][4];
        for (int ks = 0; ks < 2; ++ks)
            for (int ct = 0; ct < 4; ++ct)
                vf[ks][ct] = *(const short8*)(sV + (16 * ct + l15) * LDB + ks * 32 + quad * 8);

        f32x4 acc_s[4];
        for (int mt = 0; mt < 4; ++mt) {
            const int row = 16 * mt + l15;
            const short8 kf0 = *(const short8*)(sK + row * LDB + quad * 8);
            const short8 kf1 = *(const short8*)(sK + row * LDB + 32 + quad * 8);
            f32x4 a = (f32x4){0.f, 0.f, 0.f, 0.f};
            a = __builtin_amdgcn_mfma_f32_16x16x32_bf16(qf0, kf0, a, 0, 0, 0);
            a = __builtin_amdgcn_mfma_f32_16x16x32_bf16(qf1, kf1, a, 0, 0, 0);
            acc_s[mt] = a;
        }

        float alpha[4];
        for (int r = 0; r < 4; ++r) {
            float mx = fmaxf(fmaxf(acc_s[0][r], acc_s[1][r]), fmaxf(acc_s[2][r], acc_s[3][r]));
            mx = fmaxf(mx, __shfl_xor(mx, 1));
            mx = fmaxf(mx, __shfl_xor(mx, 2));
            mx = fmaxf(mx, __shfl_xor(mx, 4));
            mx = fmaxf(mx, __shfl_xor(mx, 8));
            const float mnew = fmaxf(m_i[r], mx);
            alpha[r] = __expf(m_i[r] - mnew);
            m_i[r] = mnew;
        }
        float rowsum[4] = {0.f, 0.f, 0.f, 0.f};
        unsigned short pb[4][4];
        for (int mt = 0; mt < 4; ++mt)
            for (int r = 0; r < 4; ++r) {
                const float p = __expf(acc_s[mt][r] - m_i[r]);
                rowsum[r] += p;
                pb[mt][r] = f2bf(p);
            }
        for (int r = 0; r < 4; ++r) {
            float s = rowsum[r];
            s += __shfl_xor(s, 1);
            s += __shfl_xor(s, 2);
            s += __shfl_xor(s, 4);
            s += __shfl_xor(s, 8);
            l_i[r] = alpha[r] * l_i[r] + s;
        }
        for (int ct = 0; ct < 4; ++ct)
            for (int r = 0; r < 4; ++r)
                acc_o[ct][r] *= alpha[r];

        for (int mt = 0; mt < 4; ++mt)
            for (int r = 0; r < 4; ++r)
                sP[(16 * w + quad * 4 + r) * LDB + l15 + 16 * mt] = pb[mt][r];
        __syncthreads();

        const short8 pf0 = *(const short8*)(sP + (16 * w + l15) * LDB + quad * 8);
        const short8 pf1 = *(const short8*)(sP + (16 * w + l15) * LDB + 32 + quad * 8);
        for (int ct = 0; ct < 4; ++ct) {
            acc_o[ct] = __builtin_amdgcn_mfma_f32_16x16x32_bf16(pf0, vf[0][ct], acc_o[ct], 0, 0, 0);
            acc_o[ct] = __builtin_amdgcn_mfma_f32_16x16x32_bf16(pf1, vf[1][ct], acc_o[ct], 0, 0, 0);
        }
    }

    float inv[4];
    for (int r = 0; r < 4; ++r) inv[r] = 1.f / l_i[r];
    for (int ct = 0; ct < 4; ++ct) {
        const int c = 16 * ct + l15;
        for (int r = 0; r < 4; ++r)
            sO[c * LDO + 16 * w + quad * 4 + r] = acc_o[ct][r] * inv[r];
    }
    __syncthreads();
    for (int cc = 0; cc < 4; ++cc) {
        const int c = c0 + 16 * cc;
        const f32x4 v = *(const f32x4*)(sO + c * LDO + 4 * mgrp);
        *(f32x4*)(Out + (size_t)b * DIM * SEQ + (size_t)c * SEQ + s0 + 4 * mgrp) = v;
    }
}

extern "C" void kernel_launch(void* const* d_in, const int* in_sizes, int n_in,
                              void* d_out, int out_size, void* d_ws, size_t ws_size,
                              hipStream_t stream) {
    const float* X = (const float*)d_in[0];
    float* Out = (float*)d_out;
    const size_t elems = (size_t)8 * SEQ * DIM;                       // 2M elements
    const size_t need  = elems * 2 * 2 + (size_t)8 * SEQ * 4 + 8 * 4; // Xbf+XbfT+Norms+MaxNorm
    if (ws_size >= need) {
        unsigned short* Xbf  = (unsigned short*)d_ws;
        unsigned short* XbfT = Xbf + elems;
        float* Norms   = (float*)(XbfT + elems);
        float* MaxNorm = Norms + (size_t)8 * SEQ;
        hipMemsetAsync(MaxNorm, 0, 8 * sizeof(float), stream);
        dim3 grid(64, 8);
        prepass2<<<grid, 256, 0, stream>>>(X, Xbf, XbfT, Norms, MaxNorm);
        attn_main<<<grid, 256, 0, stream>>>(Xbf, XbfT, Norms, MaxNorm, Out);
    } else {
        attn_fallback<<<dim3(64, 8), 256, 0, stream>>>(X, Out);
    }
}